// Round 7
// baseline (190.757 us; speedup 1.0000x reference)
//
#include <hip/hip_runtime.h>

// Graph2Col: stable stream compaction of (m=128, V=2048, R=32) int32 mapping.
// Valid (!= -1) entries first in row-major order; tail filled with -1.
// Output layout in d_out (int32): nodes_indices [total*2] then column_indices [total*3].
//
// R14: R13's goal (remove the per-block O(NB) redundant counts-scan) without
//      R13's fatal flaw. R13 elected a "last block" via prev%NB on a poisoned
//      cross-launch counter -- the elected block is NOT the last unless the
//      counter starts at 0 (harness re-poisons ws between iterations ->
//      incomplete counts scanned -> garbage excl -> OOB writes -> abort).
//      Fix: dedicated k_scan<<<1,256>>> between the two kernels. No atomics,
//      no cross-launch state: counts[] produced and consumed within one
//      iteration's launch sequence. k_scatter keeps the R13 simplifications
//      (prefix[b] uniform load, dedicated WSUM, 2 barriers) and the
//      best-measured R10 staging/copy-out (full expansion, head-aligned,
//      pure ds_read_b128 -> global dwordx4).

#define EMPTY_V (-1)

typedef int v2i __attribute__((ext_vector_type(2)));
typedef int v4i __attribute__((ext_vector_type(4)));

constexpr int TOTAL = 8388608;                 // 128*2048*32
constexpr int BLOCK = 256;
constexpr int CHUNK = 2048;                    // elements per block
constexpr int NB = TOTAL / CHUNK;              // 4096 blocks
constexpr int SUBT = CHUNK / (BLOCK * 4);      // 2 sub-tiles of 1024 elements
constexpr int NWAVE = BLOCK / 64;              // 4 waves
constexpr int PER_T = NB / BLOCK;              // 16 counts per thread in scan

// ---------------------------------------------------------------- count pass
__global__ __launch_bounds__(BLOCK) void k_count(const int* __restrict__ in,
                                                 int* __restrict__ counts) {
    const int b = blockIdx.x;
    const int tid = threadIdx.x;
    const int4* p = (const int4*)(in + (size_t)b * CHUNK);
    int c = 0;
#pragma unroll
    for (int s = 0; s < SUBT; ++s) {
        int4 v = p[s * BLOCK + tid];
        c += (v.x != EMPTY_V) + (v.y != EMPTY_V) + (v.z != EMPTY_V) + (v.w != EMPTY_V);
    }
    for (int d = 32; d; d >>= 1) c += __shfl_down(c, d, 64);
    __shared__ int ws[NWAVE];
    const int lane = tid & 63, wid = tid >> 6;
    if (lane == 0) ws[wid] = c;
    __syncthreads();
    if (tid == 0) counts[b] = ws[0] + ws[1] + ws[2] + ws[3];
}

// ------------------- single-block exclusive scan: counts[NB] -> prefix[NB]
__global__ __launch_bounds__(BLOCK) void k_scan(const int* __restrict__ counts,
                                                int* __restrict__ prefix) {
    const int tid = threadIdx.x;
    const int lane = tid & 63, wid = tid >> 6;
    int vals[PER_T];
    int ssum = 0;
    const int base = tid * PER_T;
#pragma unroll
    for (int i = 0; i < PER_T; ++i) {
        vals[i] = counts[base + i];
        ssum += vals[i];
    }
    int inc = ssum;                                 // wave inclusive scan of sums
    for (int d = 1; d < 64; d <<= 1) {
        const int t = __shfl_up(inc, d, 64);
        if (lane >= d) inc += t;
    }
    __shared__ int wtot[NWAVE];
    if (lane == 63) wtot[wid] = inc;
    __syncthreads();
    int woff = 0;
#pragma unroll
    for (int w = 0; w < NWAVE; ++w)
        if (w < wid) woff += wtot[w];
    int run = woff + (inc - ssum);                  // thread-exclusive base
#pragma unroll
    for (int i = 0; i < PER_T; ++i) {
        prefix[base + i] = run;
        run += vals[i];
    }
}

// ------- scatter: prefix[b] lookup + head-aligned staging + pure b128 copy-out
__global__ __launch_bounds__(BLOCK) void k_scatter(const int* __restrict__ in,
                                                   const int* __restrict__ prefix,
                                                   int* __restrict__ out_nodes,
                                                   int* __restrict__ out_cols) {
    const int b = blockIdx.x;
    const int tid = threadIdx.x;
    const int lane = tid & 63, wid = tid >> 6;
    const unsigned long long below = lane ? ((~0ull) >> (64 - lane)) : 0ull;

    __shared__ int s_nodes[2 * CHUNK];   // 16 KB
    __shared__ int s_cols[3 * CHUNK];    // 24 KB
    __shared__ int WSUM[SUBT * NWAVE];   // dedicated: no scratch-overlay barrier

    const int excl = prefix[b];          // uniform scalar load (L2)

    // ---- load chunk, ballots, publish per-wave totals
    int4 v[SUBT];
    int pre[SUBT];
    const int4* p = (const int4*)(in + (size_t)b * CHUNK);
#pragma unroll
    for (int s = 0; s < SUBT; ++s) {
        v[s] = p[s * BLOCK + tid];
        const unsigned long long b0 = __ballot(v[s].x != EMPTY_V);
        const unsigned long long b1 = __ballot(v[s].y != EMPTY_V);
        const unsigned long long b2 = __ballot(v[s].z != EMPTY_V);
        const unsigned long long b3 = __ballot(v[s].w != EMPTY_V);
        pre[s] = __popcll(b0 & below) + __popcll(b1 & below) +
                 __popcll(b2 & below) + __popcll(b3 & below);
        if (lane == 0)
            WSUM[s * NWAVE + wid] =
                __popcll(b0) + __popcll(b1) + __popcll(b2) + __popcll(b3);
    }
    __syncthreads();   // barrier 1: WSUM visible

    // ---- per-thread local ranks
    int myoff[SUBT];
    int acc = 0;
#pragma unroll
    for (int s = 0; s < SUBT; ++s) {
        int cs_ = 0, woff = 0;
#pragma unroll
        for (int w = 0; w < NWAVE; ++w) {
            const int x = WSUM[s * NWAVE + w];
            cs_ += x;
            if (w < wid) woff += x;
        }
        myoff[s] = acc + woff + pre[s];   // local record rank within block
        acc += cs_;
    }
    const int nv = acc;                   // blockValid

    // ---- head-aligned staging: first `head` records go straight to global,
    //      the rest staged expanded at slot (rank - head).
    const int row = b >> 5;              // 65536 elems per output row
    int head = (4 - (excl & 3)) & 3;
    if (head > nv) head = nv;
#pragma unroll
    for (int s = 0; s < SUBT; ++s) {
        int lp = myoff[s];
        const int rem0 = ((b & 31) << 11) + (s << 10) + (tid << 2);  // fi & 65535
        const int vals[4] = {v[s].x, v[s].y, v[s].z, v[s].w};
#pragma unroll
        for (int j = 0; j < 4; ++j) {
            if (vals[j] != EMPTY_V) {
                const int pp = rem0 + j;
                if (lp < head) {                       // <=3 records per block
                    const size_t g = (size_t)excl + lp;
                    out_nodes[2 * g] = row;  out_nodes[2 * g + 1] = vals[j];
                    out_cols[3 * g] = row;   out_cols[3 * g + 1] = pp >> 5;
                    out_cols[3 * g + 2] = pp & 31;
                } else {
                    const int sl = lp - head;
                    v2i nd = {row, vals[j]};
                    *(v2i*)&s_nodes[2 * sl] = nd;      // aligned ds_write_b64
                    s_cols[3 * sl] = row;
                    s_cols[3 * sl + 1] = pp >> 5;
                    s_cols[3 * sl + 2] = pp & 31;
                }
                ++lp;
            }
        }
    }
    __syncthreads();   // barrier 2: staging complete

    // ---- copy-out: both src and dst 16B-aligned -> pure b128 stream
    const int nrec = nv - head;                  // staged records (>= 0)
    const size_t g0 = (size_t)excl + head;       // g0 % 4 == 0 when nrec > 0
    {
        const int ndw = 2 * nrec, q = ndw >> 2;  // nodes: tail is 0 or 2 dwords
        v4i* dst = (v4i*)(out_nodes + 2 * g0);
        const v4i* src = (const v4i*)s_nodes;
        for (int k = tid; k < q; k += BLOCK) dst[k] = src[k];
        if ((ndw & 3) && tid < (ndw & 3))
            out_nodes[2 * g0 + 4 * q + tid] = s_nodes[4 * q + tid];
    }
    {
        const int ndw = 3 * nrec, q = ndw >> 2;  // cols: tail is 0..3 dwords
        v4i* dst = (v4i*)(out_cols + 3 * g0);
        const v4i* src = (const v4i*)s_cols;
        for (int k = tid; k < q; k += BLOCK) dst[k] = src[k];
        if (tid < (ndw & 3))
            out_cols[3 * g0 + 4 * q + tid] = s_cols[4 * q + tid];
    }

    // ---- tail: this block's invalid entries, counted from the end.
    {
        const int inv_pref = b * CHUNK - excl;            // invalids before this block
        const int start = TOTAL - inv_pref - (CHUNK - nv);
        const int end = TOTAL - inv_pref;
        for (int pos = start + tid; pos < end; pos += BLOCK) {
            out_nodes[2 * pos]     = EMPTY_V;
            out_nodes[2 * pos + 1] = EMPTY_V;
            out_cols[3 * pos]      = EMPTY_V;
            out_cols[3 * pos + 1]  = EMPTY_V;
            out_cols[3 * pos + 2]  = EMPTY_V;
        }
    }
}

extern "C" void kernel_launch(void* const* d_in, const int* in_sizes, int n_in,
                              void* d_out, int out_size, void* d_ws, size_t ws_size,
                              hipStream_t stream) {
    const int* in = (const int*)d_in[0];
    int* out = (int*)d_out;
    int* out_nodes = out;                    // [TOTAL, 2] int32
    int* out_cols = out + 2 * (size_t)TOTAL; // [TOTAL, 3] int32
    int* ws = (int*)d_ws;
    int* counts = ws;                        // [NB] 16 KB
    int* prefix = ws + NB;                   // [NB] 16 KB

    k_count<<<NB, BLOCK, 0, stream>>>(in, counts);
    k_scan<<<1, BLOCK, 0, stream>>>(counts, prefix);
    k_scatter<<<NB, BLOCK, 0, stream>>>(in, prefix, out_nodes, out_cols);
}